// Round 1
// baseline (184.339 us; speedup 1.0000x reference)
//
#include <hip/hip_runtime.h>
#include <hip/hip_bf16.h>

typedef __attribute__((ext_vector_type(8))) short short8;
typedef __attribute__((ext_vector_type(4))) float floatx4;

#define HW_TOK 4096
#define KLEN 308
#define KPAD 320
#define DH 64
#define INNER 512
#define BQ 32
#define KSTR 72      // Klds/Qlds row stride in ushort (64 + 8 pad, 16B-aligned rows)
#define VSTR 328     // Vt row stride in ushort (320 + 8 pad)
#define SSTR 332     // S row stride in floats

// round-to-nearest-even f32 -> bf16 (finite inputs only)
__device__ __forceinline__ unsigned short f2bf(float f) {
    union { float f; unsigned u; } x; x.f = f;
    unsigned u = x.u;
    return (unsigned short)((u + 0x7FFFu + ((u >> 16) & 1u)) >> 16);
}

__global__ __launch_bounds__(256)
void dd_attn_kernel(const float* __restrict__ q,
                    const float* __restrict__ k,
                    const float* __restrict__ v,
                    const float* __restrict__ dd,
                    float* __restrict__ out) {
    __shared__ unsigned short Klds[KPAD][KSTR];   // K[col][d] bf16        46080 B
    __shared__ unsigned short Vt[DH][VSTR];       // V^T[d][col] bf16      41984 B
    __shared__ unsigned short Qlds[BQ][KSTR];     // Q[row][d] bf16         4608 B
    __shared__ float S[BQ][SSTR];                 // logits / P            42496 B
    __shared__ float rscale_s[4];
    __shared__ float rowsum[BQ];

    const int tid  = threadIdx.x;
    const int lane = tid & 63;
    const int wave = tid >> 6;
    const int quad = lane >> 4;
    const int l15  = lane & 15;

    const int bid = blockIdx.x;
    const int bh = bid >> 4;        // 0..15
    const int qchunk = bid & 15;    // 0..15 -> 256 q rows each
    const int b = bh >> 3;
    const int h = bh & 7;

    const float* qp = q + ((size_t)b * HW_TOK) * INNER + h * DH;
    const float* kp = k + ((size_t)b * KLEN) * INNER + h * DH;
    const float* vp = v + ((size_t)b * KLEN) * INNER + h * DH;
    float* op = out + ((size_t)b * HW_TOK) * INNER + h * DH;

    // ---- stage K (bf16), zero-pad rows 308..319 ----
    for (int e = tid; e < KPAD * 32; e += 256) {
        int row = e >> 5, d2 = e & 31;
        float2 f = make_float2(0.f, 0.f);
        if (row < KLEN) f = *(const float2*)(kp + (size_t)row * INNER + 2 * d2);
        unsigned short lo = f2bf(f.x), hi = f2bf(f.y);
        *(unsigned int*)&Klds[row][2 * d2] = ((unsigned)hi << 16) | lo;
    }
    // ---- stage V transposed (scattered LDS writes, once per block) ----
    for (int e = tid; e < KLEN * 32; e += 256) {
        int col = e >> 5, d2 = e & 31;
        float2 f = *(const float2*)(vp + (size_t)col * INNER + 2 * d2);
        Vt[2 * d2][col]     = f2bf(f.x);
        Vt[2 * d2 + 1][col] = f2bf(f.y);
    }
    // zero V pad cols 308..319 (MFMA K reaches 319; avoid NaN garbage)
    for (int e = tid; e < DH * 32; e += 256) {
        int d = e >> 5, c = e & 31;
        if (c < KPAD - KLEN) Vt[d][KLEN + c] = 0;
    }
    // ---- region scales: rscale[r] = 4096 / (4 * sum(dd[r])) ----
    {
        float p = 0.f;
        if (wave < 4) {
            #pragma unroll
            for (int i = 0; i < 16; ++i) p += dd[wave * 1024 + lane + 64 * i];
        }
        for (int off = 32; off >= 1; off >>= 1) p += __shfl_xor(p, off);
        if (wave < 4 && lane == 0) rscale_s[wave] = 4096.0f / (4.0f * p);
    }
    __syncthreads();

    const int mt = wave >> 1;     // m-tile (q rows 16*mt..)
    const int half = wave & 1;    // column half for QK / d half-pair for PV

    for (int qt = 0; qt < 8; ++qt) {
        const int q0 = qchunk * 256 + qt * 32;
        __syncthreads();  // protect S / Qlds reuse across iterations
        // ---- stage Q tile ----
        for (int e = tid; e < 32 * 32; e += 256) {
            int row = e >> 5, d2 = e & 31;
            float2 f = *(const float2*)(qp + (size_t)(q0 + row) * INNER + 2 * d2);
            unsigned short lo = f2bf(f.x), hi = f2bf(f.y);
            *(unsigned int*)&Qlds[row][2 * d2] = ((unsigned)hi << 16) | lo;
        }
        __syncthreads();

        // ---- QK^T: each wave does 1 m-tile x 10 n-tiles ----
        {
            short8 a0 = *(const short8*)&Qlds[mt * 16 + l15][quad * 8];
            short8 a1 = *(const short8*)&Qlds[mt * 16 + l15][32 + quad * 8];
            floatx4 acc[10];
            #pragma unroll
            for (int nt = 0; nt < 10; ++nt) {
                int col = (half * 10 + nt) * 16 + l15;
                short8 b0 = *(const short8*)&Klds[col][quad * 8];
                short8 b1 = *(const short8*)&Klds[col][32 + quad * 8];
                floatx4 c = {0.f, 0.f, 0.f, 0.f};
                c = __builtin_amdgcn_mfma_f32_16x16x32_bf16(a0, b0, c, 0, 0, 0);
                c = __builtin_amdgcn_mfma_f32_16x16x32_bf16(a1, b1, c, 0, 0, 0);
                acc[nt] = c;
            }
            #pragma unroll
            for (int nt = 0; nt < 10; ++nt) {
                int colb = (half * 10 + nt) * 16 + l15;
                int rowb = mt * 16 + quad * 4;
                #pragma unroll
                for (int r = 0; r < 4; ++r) S[rowb + r][colb] = acc[nt][r];
            }
        }
        __syncthreads();

        // ---- masked scaled softmax (8 threads per row) ----
        {
            int row = tid >> 3;
            int lg = tid & 7;
            int qrow = q0 + row;
            int ii = qrow >> 6, jj = qrow & 63;
            int mi = (ii >> 1) * 32 + (jj >> 1);
            float coef[4];
            #pragma unroll
            for (int r = 0; r < 4; ++r) {
                float mv = dd[r * 1024 + mi];
                coef[r] = (mv > 0.5f) ? 0.125f * rscale_s[r] : -1.0f;  // -1 = masked flag
            }
            float m = -INFINITY;
            for (int c = lg; c < KPAD; c += 8) {
                int rg = (c < 77) ? 0 : (c < 154) ? 1 : (c < 231) ? 2 : (c < 308) ? 3 : -1;
                float sv = -INFINITY;
                if (rg >= 0 && coef[rg] > 0.f) sv = S[row][c] * coef[rg];
                S[row][c] = sv;
                m = fmaxf(m, sv);
            }
            #pragma unroll
            for (int off = 1; off < 8; off <<= 1) m = fmaxf(m, __shfl_xor(m, off));
            float l = 0.f;
            for (int c = lg; c < KPAD; c += 8) {
                float p = __expf(S[row][c] - m);   // exp(-inf)=0 for masked
                S[row][c] = p;
                l += p;
            }
            #pragma unroll
            for (int off = 1; off < 8; off <<= 1) l += __shfl_xor(l, off);
            if (lg == 0) rowsum[row] = l;
        }
        __syncthreads();

        // ---- PV: each wave 1 m-tile x 2 n-tiles (of 4), K=320 in 10 steps ----
        {
            const int nbase = half * 2;
            floatx4 oacc[2] = {{0.f,0.f,0.f,0.f},{0.f,0.f,0.f,0.f}};
            #pragma unroll
            for (int ks = 0; ks < 10; ++ks) {
                floatx4 p0 = *(const floatx4*)&S[mt * 16 + l15][ks * 32 + quad * 8];
                floatx4 p1 = *(const floatx4*)&S[mt * 16 + l15][ks * 32 + quad * 8 + 4];
                short8 a;
                #pragma unroll
                for (int t = 0; t < 4; ++t) a[t] = (short)f2bf(p0[t]);
                #pragma unroll
                for (int t = 0; t < 4; ++t) a[4 + t] = (short)f2bf(p1[t]);
                #pragma unroll
                for (int t = 0; t < 2; ++t) {
                    short8 bv = *(const short8*)&Vt[(nbase + t) * 16 + l15][ks * 32 + quad * 8];
                    oacc[t] = __builtin_amdgcn_mfma_f32_16x16x32_bf16(a, bv, oacc[t], 0, 0, 0);
                }
            }
            // ---- epilogue: normalize and store ----
            #pragma unroll
            for (int t = 0; t < 2; ++t) {
                int d = (nbase + t) * 16 + l15;
                #pragma unroll
                for (int r = 0; r < 4; ++r) {
                    int row = mt * 16 + quad * 4 + r;
                    op[(size_t)(q0 + row) * INNER + d] = oacc[t][r] / rowsum[row];
                }
            }
        }
    }
}

extern "C" void kernel_launch(void* const* d_in, const int* in_sizes, int n_in,
                              void* d_out, int out_size, void* d_ws, size_t ws_size,
                              hipStream_t stream) {
    const float* q  = (const float*)d_in[0];
    const float* k  = (const float*)d_in[1];
    const float* v  = (const float*)d_in[2];
    const float* dd = (const float*)d_in[3];
    float* out = (float*)d_out;
    dd_attn_kernel<<<dim3(256), dim3(256), 0, stream>>>(q, k, v, dd, out);
}

// Round 2
// 108.026 us; speedup vs baseline: 1.7064x; 1.7064x over previous
//
#include <hip/hip_runtime.h>
#include <hip/hip_bf16.h>

typedef __attribute__((ext_vector_type(8))) short short8;
typedef __attribute__((ext_vector_type(4))) float floatx4;

#define HW_TOK 4096
#define KLEN 308
#define KPAD 320
#define DH 64
#define INNER 512
#define KSTR 72      // Klds row stride (ushort): 64 + 8 pad, 16B aligned, 2-way banks
#define VSTR 328     // Vt row stride (ushort): 320 + 8 pad
#define PSTR 72      // P scratch row stride (ushort): 64 + 8 pad
#define NWAVE 8

// round-to-nearest-even f32 -> bf16
__device__ __forceinline__ unsigned short f2bf(float f) {
    union { float f; unsigned u; } x; x.f = f;
    unsigned u = x.u;
    return (unsigned short)((u + 0x7FFFu + ((u >> 16) & 1u)) >> 16);
}

__global__ __launch_bounds__(512)
void dd_attn_kernel(const float* __restrict__ q,
                    const float* __restrict__ k,
                    const float* __restrict__ v,
                    const float* __restrict__ dd,
                    float* __restrict__ out) {
    __shared__ unsigned short Klds[KPAD][KSTR];          // 46080 B
    __shared__ unsigned short Vt[DH][VSTR];              // 41984 B
    __shared__ unsigned short Pw[NWAVE][2][16][PSTR];    // 36864 B (per-wave, dbuf)
    __shared__ float rscale_s[4];

    const int tid  = threadIdx.x;
    const int lane = tid & 63;
    const int wave = tid >> 6;
    const int quad = lane >> 4;
    const int l15  = lane & 15;

    const int bid = blockIdx.x;
    const int bh  = bid >> 4;      // 0..15
    const int grp = bid & 15;      // 16 q-tile-groups per (b,h)
    const int b = bh >> 3;
    const int h = bh & 7;

    const float* qp = q + (size_t)b * HW_TOK * INNER + h * DH;
    const float* kp = k + (size_t)b * KLEN * INNER + h * DH;
    const float* vp = v + (size_t)b * KLEN * INNER + h * DH;
    float* op = out + (size_t)b * HW_TOK * INNER + h * DH;

    // ---- stage K bf16 (zero-pad rows 308..319) ----
    for (int e = tid; e < KPAD * 32; e += 512) {
        int row = e >> 5, d2 = e & 31;
        float2 f = make_float2(0.f, 0.f);
        if (row < KLEN) f = *(const float2*)(kp + (size_t)row * INNER + 2 * d2);
        *(unsigned*)&Klds[row][2 * d2] = ((unsigned)f2bf(f.y) << 16) | f2bf(f.x);
    }
    // ---- stage V^T bf16 ----
    for (int e = tid; e < KLEN * 32; e += 512) {
        int col = e >> 5, d2 = e & 31;
        float2 f = *(const float2*)(vp + (size_t)col * INNER + 2 * d2);
        Vt[2 * d2][col]     = f2bf(f.x);
        Vt[2 * d2 + 1][col] = f2bf(f.y);
    }
    for (int e = tid; e < DH * 12; e += 512) {   // zero pad cols 308..319
        int d = e / 12, c = e % 12;
        Vt[d][KLEN + c] = 0;
    }
    // ---- region scales ----
    if (wave < 4) {
        float p = 0.f;
        #pragma unroll
        for (int i = 0; i < 16; ++i) p += dd[wave * 1024 + lane + 64 * i];
        #pragma unroll
        for (int off = 32; off >= 1; off >>= 1) p += __shfl_xor(p, off);
        if (lane == 0) rscale_s[wave] = 4096.0f / (4.0f * p);
    }
    __syncthreads();   // the ONLY barrier

    const float rs0 = rscale_s[0], rs1 = rscale_s[1], rs2 = rscale_s[2], rs3 = rscale_s[3];
    const float rsv[4] = {rs0, rs1, rs2, rs3};

    for (int it = 0; it < 2; ++it) {
        const int q0 = (grp * 16 + wave * 2 + it) * 16;

        // ---- Q A-fragments straight from global (f32 -> bf16) ----
        const float* qr = qp + (size_t)(q0 + l15) * INNER + quad * 8;
        float4 f0 = *(const float4*)(qr);
        float4 f1 = *(const float4*)(qr + 4);
        float4 f2 = *(const float4*)(qr + 32);
        float4 f3 = *(const float4*)(qr + 36);
        short8 a0, a1;
        a0[0]=(short)f2bf(f0.x); a0[1]=(short)f2bf(f0.y); a0[2]=(short)f2bf(f0.z); a0[3]=(short)f2bf(f0.w);
        a0[4]=(short)f2bf(f1.x); a0[5]=(short)f2bf(f1.y); a0[6]=(short)f2bf(f1.z); a0[7]=(short)f2bf(f1.w);
        a1[0]=(short)f2bf(f2.x); a1[1]=(short)f2bf(f2.y); a1[2]=(short)f2bf(f2.z); a1[3]=(short)f2bf(f2.w);
        a1[4]=(short)f2bf(f3.x); a1[5]=(short)f2bf(f3.y); a1[6]=(short)f2bf(f3.z); a1[7]=(short)f2bf(f3.w);

        // ---- QK^T: 20 n-tiles, all independent ----
        floatx4 acc[20];
        #pragma unroll
        for (int nt = 0; nt < 20; ++nt) {
            int col = nt * 16 + l15;
            short8 b0 = *(const short8*)&Klds[col][quad * 8];
            short8 b1 = *(const short8*)&Klds[col][32 + quad * 8];
            floatx4 c = {0.f, 0.f, 0.f, 0.f};
            c = __builtin_amdgcn_mfma_f32_16x16x32_bf16(a0, b0, c, 0, 0, 0);
            c = __builtin_amdgcn_mfma_f32_16x16x32_bf16(a1, b1, c, 0, 0, 0);
            acc[nt] = c;
        }

        // ---- per-row/region coefficients (mask bit * scale, or -1 = masked) ----
        float coef[4][4];
        #pragma unroll
        for (int r = 0; r < 4; ++r) {
            int qrow = q0 + quad * 4 + r;
            int mi = (qrow >> 7) * 32 + ((qrow & 63) >> 1);   // nearest-exact 64->32
            #pragma unroll
            for (int rg = 0; rg < 4; ++rg) {
                float mv = dd[rg * 1024 + mi];
                coef[r][rg] = (mv > 0.5f) ? 0.125f * rsv[rg] : -1.0f;
            }
        }

        // ---- mask + scale + row-max (in C-layout registers) ----
        float mx[4] = {-INFINITY, -INFINITY, -INFINITY, -INFINITY};
        #pragma unroll
        for (int nt = 0; nt < 20; ++nt) {
            #pragma unroll
            for (int r = 0; r < 4; ++r) {
                float c;
                if      (nt <  4) c = coef[r][0];
                else if (nt == 4) c = (l15 < 13) ? coef[r][0] : coef[r][1];
                else if (nt <  9) c = coef[r][1];
                else if (nt == 9) c = (l15 < 10) ? coef[r][1] : coef[r][2];
                else if (nt < 14) c = coef[r][2];
                else if (nt ==14) c = (l15 <  7) ? coef[r][2] : coef[r][3];
                else if (nt < 19) c = coef[r][3];
                else              c = (l15 <  4) ? coef[r][3] : -1.0f;
                float sv = (c > 0.f) ? acc[nt][r] * c : -INFINITY;
                acc[nt][r] = sv;
                mx[r] = fmaxf(mx[r], sv);
            }
        }
        #pragma unroll
        for (int off = 1; off < 16; off <<= 1) {
            #pragma unroll
            for (int r = 0; r < 4; ++r) mx[r] = fmaxf(mx[r], __shfl_xor(mx[r], off));
        }

        // ---- exp + row-sum ----
        float sm[4] = {0.f, 0.f, 0.f, 0.f};
        #pragma unroll
        for (int nt = 0; nt < 20; ++nt) {
            #pragma unroll
            for (int r = 0; r < 4; ++r) {
                float p = __expf(acc[nt][r] - mx[r]);   // exp(-inf)=0 for masked
                acc[nt][r] = p;
                sm[r] += p;
            }
        }
        #pragma unroll
        for (int off = 1; off < 16; off <<= 1) {
            #pragma unroll
            for (int r = 0; r < 4; ++r) sm[r] += __shfl_xor(sm[r], off);
        }
        float inv[4];
        #pragma unroll
        for (int r = 0; r < 4; ++r) inv[r] = 1.0f / sm[r];

        // ---- PV: 5 chunks of 64 cols; P transposed via per-wave LDS scratch ----
        floatx4 oacc[4] = {{0.f,0.f,0.f,0.f},{0.f,0.f,0.f,0.f},{0.f,0.f,0.f,0.f},{0.f,0.f,0.f,0.f}};
        #pragma unroll
        for (int c5 = 0; c5 < 5; ++c5) {
            const int buf = c5 & 1;
            #pragma unroll
            for (int nt2 = 0; nt2 < 4; ++nt2) {
                int nt = c5 * 4 + nt2;
                #pragma unroll
                for (int r = 0; r < 4; ++r)
                    Pw[wave][buf][quad * 4 + r][nt2 * 16 + l15] = f2bf(acc[nt][r]);
            }
            #pragma unroll
            for (int ks = 0; ks < 2; ++ks) {
                short8 pa = *(const short8*)&Pw[wave][buf][l15][ks * 32 + quad * 8];
                #pragma unroll
                for (int n = 0; n < 4; ++n) {
                    short8 bv = *(const short8*)&Vt[n * 16 + l15][c5 * 64 + ks * 32 + quad * 8];
                    oacc[n] = __builtin_amdgcn_mfma_f32_16x16x32_bf16(pa, bv, oacc[n], 0, 0, 0);
                }
            }
        }

        // ---- normalize + store (C-layout) ----
        #pragma unroll
        for (int n = 0; n < 4; ++n) {
            #pragma unroll
            for (int r = 0; r < 4; ++r) {
                op[(size_t)(q0 + quad * 4 + r) * INNER + n * 16 + l15] = oacc[n][r] * inv[r];
            }
        }
    }
}

extern "C" void kernel_launch(void* const* d_in, const int* in_sizes, int n_in,
                              void* d_out, int out_size, void* d_ws, size_t ws_size,
                              hipStream_t stream) {
    const float* q  = (const float*)d_in[0];
    const float* k  = (const float*)d_in[1];
    const float* v  = (const float*)d_in[2];
    const float* dd = (const float*)d_in[3];
    float* out = (float*)d_out;
    dd_attn_kernel<<<dim3(256), dim3(512), 0, stream>>>(q, k, v, dd, out);
}